// Round 2
// baseline (18035.895 us; speedup 1.0000x reference)
//
#include <hip/hip_runtime.h>
#include <hip/hip_cooperative_groups.h>

namespace cg = cooperative_groups;

typedef __attribute__((ext_vector_type(8))) short bf16x8;
typedef __attribute__((ext_vector_type(4))) float f32x4;

#define MFMA16(a, b, c) __builtin_amdgcn_mfma_f32_16x16x32_bf16(a, b, c, 0, 0, 0)

#define HSZ (64 * 2048)   // one h buffer (elements)

__device__ __forceinline__ unsigned short f2bf(float v) {
    unsigned int u = __float_as_uint(v);
    u += 0x7fffu + ((u >> 16) & 1u);   // round-to-nearest-even
    return (unsigned short)(u >> 16);
}
__device__ __forceinline__ float bf2f(unsigned short b) {
    return __uint_as_float(((unsigned int)b) << 16);
}

// ---------------- prep: split weights into bf16 hi/lo, fuse biases, zero h ----------------
__global__ __launch_bounds__(256) void rnn_prep(
    const float* __restrict__ Ww, const float* __restrict__ Wb,
    const float* __restrict__ Uw, const float* __restrict__ Ub,
    const float* __restrict__ bv,
    unsigned short* __restrict__ U_hi, unsigned short* __restrict__ U_lo,
    unsigned short* __restrict__ W_hi, unsigned short* __restrict__ W_lo,
    float* __restrict__ bias,
    unsigned short* __restrict__ h_hi, unsigned short* __restrict__ h_lo)
{
    size_t i = (size_t)blockIdx.x * 256 + threadIdx.x;
    if (i < (size_t)2048 * 2048) {
        float v = Uw[i];
        unsigned short hi = f2bf(v);
        U_hi[i] = hi;
        U_lo[i] = f2bf(v - bf2f(hi));
    }
    if (i < (size_t)2048 * 1024) {
        float v = Ww[i];
        unsigned short hi = f2bf(v);
        W_hi[i] = hi;
        W_lo[i] = f2bf(v - bf2f(hi));
    }
    if (i < 2 * HSZ) { h_hi[i] = 0; h_lo[i] = 0; }   // zero BOTH double buffers
    if (i < 2048) bias[i] = Wb[i] + Ub[i] + bv[i];
}

// ---------------- phase B: Xp = X @ Ww^T + bias  (M=32768, N=2048, K=1024) ----------------
// 128x128 tile per wg, 4 waves each 64x64, BK=64, 3-pass bf16x2 MFMA.
#define PB_PAD 72  // LDS row stride in elems (144B): 2-way-max bank conflicts, 16B aligned

__global__ __launch_bounds__(256, 2) void rnn_xp_gemm(
    const float* __restrict__ X,
    const unsigned short* __restrict__ W_hi, const unsigned short* __restrict__ W_lo,
    const float* __restrict__ bias, float* __restrict__ Xp)
{
    __shared__ unsigned short a_hi[128 * PB_PAD], a_lo[128 * PB_PAD];
    __shared__ unsigned short b_hi[128 * PB_PAD], b_lo[128 * PB_PAD];

    const int wg = blockIdx.x;
    const int nblk = (wg & 15) << 7;   // 16 col blocks
    const int mblk = (wg >> 4) << 7;   // 256 row blocks
    const int tid = threadIdx.x;
    const int lane = tid & 63, w = tid >> 6;
    const int wm = (w & 1) << 6, wn = (w >> 1) << 6;
    const int lhi = lane >> 4, llo = lane & 15;

    f32x4 acc[4][4] = {};

    const int srow = tid >> 1;          // 0..127
    const int skh  = (tid & 1) << 5;    // 0 or 32 within BK=64

    for (int kb = 0; kb < 1024; kb += 64) {
        __syncthreads();
        // stage A (fp32 -> bf16 hi/lo on the fly)
        {
            const float* src = X + (size_t)(mblk + srow) * 1024 + kb + skh;
            #pragma unroll
            for (int j = 0; j < 4; ++j) {
                bf16x8 vh, vl;
                #pragma unroll
                for (int e = 0; e < 8; ++e) {
                    float v = src[j * 8 + e];
                    unsigned short hi = f2bf(v);
                    vh[e] = (short)hi;
                    vl[e] = (short)f2bf(v - bf2f(hi));
                }
                *(bf16x8*)&a_hi[srow * PB_PAD + skh + j * 8] = vh;
                *(bf16x8*)&a_lo[srow * PB_PAD + skh + j * 8] = vl;
            }
        }
        // stage B (already bf16 hi/lo in ws)
        {
            const unsigned short* sh = W_hi + (size_t)(nblk + srow) * 1024 + kb + skh;
            const unsigned short* sl = W_lo + (size_t)(nblk + srow) * 1024 + kb + skh;
            #pragma unroll
            for (int j = 0; j < 4; ++j) {
                *(bf16x8*)&b_hi[srow * PB_PAD + skh + j * 8] = *(const bf16x8*)&sh[j * 8];
                *(bf16x8*)&b_lo[srow * PB_PAD + skh + j * 8] = *(const bf16x8*)&sl[j * 8];
            }
        }
        __syncthreads();

        #pragma unroll
        for (int ks = 0; ks < 2; ++ks) {
            const int koff = ks * 32 + lhi * 8;
            bf16x8 afh[4], afl[4], bfh[4], bfl[4];
            #pragma unroll
            for (int m = 0; m < 4; ++m) {
                afh[m] = *(const bf16x8*)&a_hi[(wm + m * 16 + llo) * PB_PAD + koff];
                afl[m] = *(const bf16x8*)&a_lo[(wm + m * 16 + llo) * PB_PAD + koff];
            }
            #pragma unroll
            for (int n = 0; n < 4; ++n) {
                bfh[n] = *(const bf16x8*)&b_hi[(wn + n * 16 + llo) * PB_PAD + koff];
                bfl[n] = *(const bf16x8*)&b_lo[(wn + n * 16 + llo) * PB_PAD + koff];
            }
            #pragma unroll
            for (int m = 0; m < 4; ++m) {
                #pragma unroll
                for (int n = 0; n < 4; ++n) {
                    acc[m][n] = MFMA16(afh[m], bfh[n], acc[m][n]);
                    acc[m][n] = MFMA16(afh[m], bfl[n], acc[m][n]);
                    acc[m][n] = MFMA16(afl[m], bfh[n], acc[m][n]);
                }
            }
        }
    }

    // epilogue: add bias, write fp32
    #pragma unroll
    for (int n = 0; n < 4; ++n) {
        const int col = nblk + wn + n * 16 + llo;
        const float bvv = bias[col];
        #pragma unroll
        for (int m = 0; m < 4; ++m) {
            const int row0 = mblk + wm + m * 16 + lhi * 4;
            #pragma unroll
            for (int r = 0; r < 4; ++r)
                Xp[(size_t)(row0 + r) * 2048 + col] = acc[m][n][r] + bvv;
        }
    }
}

// ---------------- phase C: recurrent h_t = tanh(Xp[t] + h_{t-1} @ Uw^T) ----------------
// 256 wgs x 512 thr (8 waves). wg = (16-row block mq, 32-col stripe sp).
// wave w = K-chunk of 256; U hi/lo fragments live in VGPRs across all 512 steps.
// h is DOUBLE-BUFFERED: step t reads buf[t&1], writes buf[(t+1)&1]. The single
// grid.sync() per step is then race-free (writes touch a buffer nobody reads
// this step; next step's reads are after the sync).
__global__ __launch_bounds__(512, 2) void rnn_recur(
    const unsigned short* __restrict__ U_hi, const unsigned short* __restrict__ U_lo,
    unsigned short* __restrict__ h_hi, unsigned short* __restrict__ h_lo,
    float* __restrict__ Out)
{
    const int W = blockIdx.x;      // 0..255
    const int mq = W & 3;          // 16-row block of batch
    const int sp = W >> 2;         // 0..63: 32-col stripe
    const int tid = threadIdx.x;
    const int w = tid >> 6, lane = tid & 63;
    const int lhi = lane >> 4, llo = lane & 15;
    const int k0 = w << 8;         // 256 K per wave
    const int n0 = sp << 5;        // 32 cols

    // preload U fragments into registers: ks 0..7, ntile 0..1, hi+lo
    bf16x8 ubh[8][2], ubl[8][2];
    #pragma unroll
    for (int ks = 0; ks < 8; ++ks) {
        #pragma unroll
        for (int n = 0; n < 2; ++n) {
            size_t off = (size_t)(n0 + n * 16 + llo) * 2048 + k0 + ks * 32 + lhi * 8;
            ubh[ks][n] = *(const bf16x8*)(U_hi + off);
            ubl[ks][n] = *(const bf16x8*)(U_lo + off);
        }
    }

    __shared__ float red[8][16][32];
    const int arow = (mq * 16 + llo) * 2048;

    const int colall = tid & 31;
    const int rrow = tid >> 5;             // 0..15
    const int b_out = mq * 16 + rrow;
    const int ng = n0 + colall;
    const size_t hidx = (size_t)b_out * 2048 + ng;

    cg::grid_group grid = cg::this_grid();

    for (int t = 0; t < 512; ++t) {
        const int cur = t & 1, nxt = cur ^ 1;
        const unsigned short* hh_r = h_hi + cur * HSZ;
        const unsigned short* hl_r = h_lo + cur * HSZ;
        unsigned short* hh_w = h_hi + nxt * HSZ;
        unsigned short* hl_w = h_lo + nxt * HSZ;

        f32x4 acc0 = {0, 0, 0, 0}, acc1 = {0, 0, 0, 0};
        #pragma unroll
        for (int ks = 0; ks < 8; ++ks) {
            const int k = k0 + ks * 32 + lhi * 8;
            bf16x8 ah = *(const bf16x8*)(hh_r + arow + k);
            bf16x8 al = *(const bf16x8*)(hl_r + arow + k);
            acc0 = MFMA16(ah, ubh[ks][0], acc0);
            acc0 = MFMA16(ah, ubl[ks][0], acc0);
            acc0 = MFMA16(al, ubh[ks][0], acc0);
            acc1 = MFMA16(ah, ubh[ks][1], acc1);
            acc1 = MFMA16(ah, ubl[ks][1], acc1);
            acc1 = MFMA16(al, ubh[ks][1], acc1);
        }
        #pragma unroll
        for (int r = 0; r < 4; ++r) {
            red[w][lhi * 4 + r][llo]      = acc0[r];
            red[w][lhi * 4 + r][16 + llo] = acc1[r];
        }
        __syncthreads();
        float s = 0.f;
        #pragma unroll
        for (int q = 0; q < 8; ++q) s += red[q][rrow][colall];
        const size_t oidx = ((size_t)t * 64 + b_out) * 2048 + ng;
        const float pre = s + Out[oidx];
        const float hv = tanhf(pre);
        Out[oidx] = hv;
        const unsigned short hh = f2bf(hv);
        hh_w[hidx] = hh;
        hl_w[hidx] = f2bf(hv - bf2f(hh));
        grid.sync();  // h_t (in nxt) fully visible device-wide before step t+1
    }
}

// ---------------- launcher ----------------
extern "C" void kernel_launch(void* const* d_in, const int* in_sizes, int n_in,
                              void* d_out, int out_size, void* d_ws, size_t ws_size,
                              hipStream_t stream)
{
    const float* X  = (const float*)d_in[0];
    const float* Ww = (const float*)d_in[1];
    const float* Wb = (const float*)d_in[2];
    const float* Uw = (const float*)d_in[3];
    const float* Ub = (const float*)d_in[4];
    const float* bv = (const float*)d_in[5];
    float* Out = (float*)d_out;

    unsigned short* U_hi = (unsigned short*)d_ws;
    unsigned short* U_lo = U_hi + (size_t)2048 * 2048;
    unsigned short* W_hi = U_lo + (size_t)2048 * 2048;
    unsigned short* W_lo = W_hi + (size_t)2048 * 1024;
    float* bias = (float*)(W_lo + (size_t)2048 * 1024);
    unsigned short* h_hi = (unsigned short*)(bias + 2048);   // [2][HSZ]
    unsigned short* h_lo = h_hi + 2 * HSZ;                   // [2][HSZ]

    rnn_prep<<<16384, 256, 0, stream>>>(Ww, Wb, Uw, Ub, bv,
                                        U_hi, U_lo, W_hi, W_lo, bias, h_hi, h_lo);

    rnn_xp_gemm<<<4096, 256, 0, stream>>>(X, W_hi, W_lo, bias, Out);

    void* args[] = { (void*)&U_hi, (void*)&U_lo, (void*)&h_hi, (void*)&h_lo, (void*)&Out };
    hipLaunchCooperativeKernel((const void*)rnn_recur, dim3(256), dim3(512), args, 0, stream);
}

// Round 3
// 5387.624 us; speedup vs baseline: 3.3477x; 3.3477x over previous
//
#include <hip/hip_runtime.h>

typedef __attribute__((ext_vector_type(8))) short bf16x8;
typedef __attribute__((ext_vector_type(4))) float f32x4;

#define MFMA16(a, b, c) __builtin_amdgcn_mfma_f32_16x16x32_bf16(a, b, c, 0, 0, 0)

#define HSZ (64 * 2048)     // one h buffer (elements)
#define NBLK 256            // recur grid
#define REL_IDX (NBLK * 16) // release word index in flags

__device__ __forceinline__ unsigned short f2bf(float v) {
    unsigned int u = __float_as_uint(v);
    u += 0x7fffu + ((u >> 16) & 1u);   // round-to-nearest-even
    return (unsigned short)(u >> 16);
}
__device__ __forceinline__ float bf2f(unsigned short b) {
    return __uint_as_float(((unsigned int)b) << 16);
}

// coherent (L1/L2-bypassing, Infinity-Cache-point) accessors
__device__ __forceinline__ unsigned long long ald64(const void* p) {
    return __hip_atomic_load((const unsigned long long*)p, __ATOMIC_RELAXED,
                             __HIP_MEMORY_SCOPE_AGENT);
}
__device__ __forceinline__ unsigned int ald32(const void* p) {
    return __hip_atomic_load((const unsigned int*)p, __ATOMIC_RELAXED,
                             __HIP_MEMORY_SCOPE_AGENT);
}
__device__ __forceinline__ void ast32(void* p, unsigned int v) {
    __hip_atomic_store((unsigned int*)p, v, __ATOMIC_RELAXED,
                       __HIP_MEMORY_SCOPE_AGENT);
}

// ---------------- prep: split weights into bf16 hi/lo, fuse biases, zero h+flags ----------------
__global__ __launch_bounds__(256) void rnn_prep(
    const float* __restrict__ Ww, const float* __restrict__ Wb,
    const float* __restrict__ Uw, const float* __restrict__ Ub,
    const float* __restrict__ bv,
    unsigned short* __restrict__ U_hi, unsigned short* __restrict__ U_lo,
    unsigned short* __restrict__ W_hi, unsigned short* __restrict__ W_lo,
    float* __restrict__ bias,
    unsigned short* __restrict__ h_hi, unsigned short* __restrict__ h_lo,
    unsigned int* __restrict__ flags)
{
    size_t i = (size_t)blockIdx.x * 256 + threadIdx.x;
    if (i < (size_t)2048 * 2048) {
        float v = Uw[i];
        unsigned short hi = f2bf(v);
        U_hi[i] = hi;
        U_lo[i] = f2bf(v - bf2f(hi));
    }
    if (i < (size_t)2048 * 1024) {
        float v = Ww[i];
        unsigned short hi = f2bf(v);
        W_hi[i] = hi;
        W_lo[i] = f2bf(v - bf2f(hi));
    }
    if (i < 2 * HSZ) { h_hi[i] = 0; h_lo[i] = 0; }   // zero BOTH double buffers
    if (i < 2048) bias[i] = Wb[i] + Ub[i] + bv[i];
    if (i < REL_IDX + 16) ast32(&flags[i], 0);       // coherent zero of barrier flags
}

// ---------------- phase B: Xp = X @ Ww^T + bias  (M=32768, N=2048, K=1024) ----------------
#define PB_PAD 72  // LDS row stride in elems (144B): 2-way-max bank conflicts, 16B aligned

__global__ __launch_bounds__(256, 2) void rnn_xp_gemm(
    const float* __restrict__ X,
    const unsigned short* __restrict__ W_hi, const unsigned short* __restrict__ W_lo,
    const float* __restrict__ bias, float* __restrict__ Xp)
{
    __shared__ unsigned short a_hi[128 * PB_PAD], a_lo[128 * PB_PAD];
    __shared__ unsigned short b_hi[128 * PB_PAD], b_lo[128 * PB_PAD];

    const int wg = blockIdx.x;
    const int nblk = (wg & 15) << 7;   // 16 col blocks
    const int mblk = (wg >> 4) << 7;   // 256 row blocks
    const int tid = threadIdx.x;
    const int lane = tid & 63, w = tid >> 6;
    const int wm = (w & 1) << 6, wn = (w >> 1) << 6;
    const int lhi = lane >> 4, llo = lane & 15;

    f32x4 acc[4][4] = {};

    const int srow = tid >> 1;          // 0..127
    const int skh  = (tid & 1) << 5;    // 0 or 32 within BK=64

    for (int kb = 0; kb < 1024; kb += 64) {
        __syncthreads();
        {
            const float* src = X + (size_t)(mblk + srow) * 1024 + kb + skh;
            #pragma unroll
            for (int j = 0; j < 4; ++j) {
                bf16x8 vh, vl;
                #pragma unroll
                for (int e = 0; e < 8; ++e) {
                    float v = src[j * 8 + e];
                    unsigned short hi = f2bf(v);
                    vh[e] = (short)hi;
                    vl[e] = (short)f2bf(v - bf2f(hi));
                }
                *(bf16x8*)&a_hi[srow * PB_PAD + skh + j * 8] = vh;
                *(bf16x8*)&a_lo[srow * PB_PAD + skh + j * 8] = vl;
            }
        }
        {
            const unsigned short* sh = W_hi + (size_t)(nblk + srow) * 1024 + kb + skh;
            const unsigned short* sl = W_lo + (size_t)(nblk + srow) * 1024 + kb + skh;
            #pragma unroll
            for (int j = 0; j < 4; ++j) {
                *(bf16x8*)&b_hi[srow * PB_PAD + skh + j * 8] = *(const bf16x8*)&sh[j * 8];
                *(bf16x8*)&b_lo[srow * PB_PAD + skh + j * 8] = *(const bf16x8*)&sl[j * 8];
            }
        }
        __syncthreads();

        #pragma unroll
        for (int ks = 0; ks < 2; ++ks) {
            const int koff = ks * 32 + lhi * 8;
            bf16x8 afh[4], afl[4], bfh[4], bfl[4];
            #pragma unroll
            for (int m = 0; m < 4; ++m) {
                afh[m] = *(const bf16x8*)&a_hi[(wm + m * 16 + llo) * PB_PAD + koff];
                afl[m] = *(const bf16x8*)&a_lo[(wm + m * 16 + llo) * PB_PAD + koff];
            }
            #pragma unroll
            for (int n = 0; n < 4; ++n) {
                bfh[n] = *(const bf16x8*)&b_hi[(wn + n * 16 + llo) * PB_PAD + koff];
                bfl[n] = *(const bf16x8*)&b_lo[(wn + n * 16 + llo) * PB_PAD + koff];
            }
            #pragma unroll
            for (int m = 0; m < 4; ++m) {
                #pragma unroll
                for (int n = 0; n < 4; ++n) {
                    acc[m][n] = MFMA16(afh[m], bfh[n], acc[m][n]);
                    acc[m][n] = MFMA16(afh[m], bfl[n], acc[m][n]);
                    acc[m][n] = MFMA16(afl[m], bfh[n], acc[m][n]);
                }
            }
        }
    }

    #pragma unroll
    for (int n = 0; n < 4; ++n) {
        const int col = nblk + wn + n * 16 + llo;
        const float bvv = bias[col];
        #pragma unroll
        for (int m = 0; m < 4; ++m) {
            const int row0 = mblk + wm + m * 16 + lhi * 4;
            #pragma unroll
            for (int r = 0; r < 4; ++r)
                Xp[(size_t)(row0 + r) * 2048 + col] = acc[m][n][r] + bvv;
        }
    }
}

// ---------------- phase C: recurrent h_t = tanh(Xp[t] + h_{t-1} @ Uw^T) ----------------
// 256 wgs x 512 thr. Custom contention-free epoch barrier (no cg::grid_sync, no fences):
// all cross-block h traffic uses relaxed AGENT-scope atomics (coherent at IF$, bypass L1/L2);
// __syncthreads() drains vmcnt so the arrive flag implies h-store visibility.
__global__ __launch_bounds__(512, 2) void rnn_recur(
    const unsigned short* __restrict__ U_hi, const unsigned short* __restrict__ U_lo,
    unsigned short* __restrict__ h_hi, unsigned short* __restrict__ h_lo,
    float* __restrict__ Out, unsigned int* __restrict__ flags)
{
    const int W = blockIdx.x;      // 0..255
    const int mq = W & 3;          // 16-row block of batch
    const int sp = W >> 2;         // 0..63: 32-col stripe
    const int tid = threadIdx.x;
    const int w = tid >> 6, lane = tid & 63;
    const int lhi = lane >> 4, llo = lane & 15;
    const int k0 = w << 8;         // 256 K per wave
    const int n0 = sp << 5;        // 32 cols

    // preload U fragments into registers (plain loads, L2-warm) and PIN them:
    bf16x8 ubh[8][2], ubl[8][2];
    #pragma unroll
    for (int ks = 0; ks < 8; ++ks) {
        #pragma unroll
        for (int n = 0; n < 2; ++n) {
            size_t off = (size_t)(n0 + n * 16 + llo) * 2048 + k0 + ks * 32 + lhi * 8;
            ubh[ks][n] = *(const bf16x8*)(U_hi + off);
            ubl[ks][n] = *(const bf16x8*)(U_lo + off);
            asm volatile("" : "+v"(ubh[ks][n]), "+v"(ubl[ks][n]));
        }
    }

    __shared__ float red[8][16][32];
    const int arow = (mq * 16 + llo) * 2048;

    const int colall = tid & 31;
    const int rrow = tid >> 5;             // 0..15
    const int b_out = mq * 16 + rrow;
    const int ng = n0 + colall;
    const size_t hidx = (size_t)b_out * 2048 + ng;

    union Pack { unsigned long long q[2]; bf16x8 v; };

    for (int t = 0; t < 512; ++t) {
        const int cur = t & 1, nxt = cur ^ 1;
        const unsigned short* hh_r = h_hi + cur * HSZ;
        const unsigned short* hl_r = h_lo + cur * HSZ;
        unsigned short* hh_w = h_hi + nxt * HSZ;
        unsigned short* hl_w = h_lo + nxt * HSZ;

        f32x4 acc0 = {0, 0, 0, 0}, acc1 = {0, 0, 0, 0};
        #pragma unroll
        for (int ks = 0; ks < 8; ++ks) {
            const int k = k0 + ks * 32 + lhi * 8;
            Pack ph, pl;
            ph.q[0] = ald64(hh_r + arow + k);
            ph.q[1] = ald64(hh_r + arow + k + 4);
            pl.q[0] = ald64(hl_r + arow + k);
            pl.q[1] = ald64(hl_r + arow + k + 4);
            acc0 = MFMA16(ph.v, ubh[ks][0], acc0);
            acc0 = MFMA16(ph.v, ubl[ks][0], acc0);
            acc0 = MFMA16(pl.v, ubh[ks][0], acc0);
            acc1 = MFMA16(ph.v, ubh[ks][1], acc1);
            acc1 = MFMA16(ph.v, ubl[ks][1], acc1);
            acc1 = MFMA16(pl.v, ubh[ks][1], acc1);
        }
        #pragma unroll
        for (int r = 0; r < 4; ++r) {
            red[w][lhi * 4 + r][llo]      = acc0[r];
            red[w][lhi * 4 + r][16 + llo] = acc1[r];
        }
        __syncthreads();
        float s = 0.f;
        #pragma unroll
        for (int q = 0; q < 8; ++q) s += red[q][rrow][colall];
        const size_t oidx = ((size_t)t * 64 + b_out) * 2048 + ng;
        const float pre = s + Out[oidx];
        const float hv = tanhf(pre);
        Out[oidx] = hv;

        // pack pairs of adjacent columns into u32 coherent stores
        const unsigned int hhp = f2bf(hv);
        const unsigned int hlp = f2bf(hv - bf2f((unsigned short)hhp));
        const unsigned int hh_o = (unsigned int)__shfl_xor((int)hhp, 1);
        const unsigned int hl_o = (unsigned int)__shfl_xor((int)hlp, 1);
        if (!(colall & 1)) {
            ast32((void*)(hh_w + hidx), hhp | (hh_o << 16));
            ast32((void*)(hl_w + hidx), hlp | (hl_o << 16));
        }

        // ---- epoch barrier (contention-free) ----
        __syncthreads();   // drains vmcnt: all this block's h-stores are visible at IF$
        if (tid == 0) ast32(&flags[W * 16], (unsigned)(t + 1));
        if (W == 0) {
            if (tid < NBLK) {
                while (ald32(&flags[tid * 16]) < (unsigned)(t + 1))
                    __builtin_amdgcn_s_sleep(1);
            }
            __syncthreads();
            if (tid == 0) ast32(&flags[REL_IDX], (unsigned)(t + 1));
        }
        if (tid == 0) {
            while (ald32(&flags[REL_IDX]) < (unsigned)(t + 1))
                __builtin_amdgcn_s_sleep(1);
        }
        __syncthreads();
    }
}

// ---------------- launcher ----------------
extern "C" void kernel_launch(void* const* d_in, const int* in_sizes, int n_in,
                              void* d_out, int out_size, void* d_ws, size_t ws_size,
                              hipStream_t stream)
{
    const float* X  = (const float*)d_in[0];
    const float* Ww = (const float*)d_in[1];
    const float* Wb = (const float*)d_in[2];
    const float* Uw = (const float*)d_in[3];
    const float* Ub = (const float*)d_in[4];
    const float* bv = (const float*)d_in[5];
    float* Out = (float*)d_out;

    unsigned short* U_hi = (unsigned short*)d_ws;
    unsigned short* U_lo = U_hi + (size_t)2048 * 2048;
    unsigned short* W_hi = U_lo + (size_t)2048 * 2048;
    unsigned short* W_lo = W_hi + (size_t)2048 * 1024;
    float* bias = (float*)(W_lo + (size_t)2048 * 1024);
    unsigned short* h_hi = (unsigned short*)(bias + 2048);   // [2][HSZ]
    unsigned short* h_lo = h_hi + 2 * HSZ;                   // [2][HSZ]
    unsigned int* flags = (unsigned int*)(h_lo + 2 * HSZ);   // [256*16 + 16]

    rnn_prep<<<16384, 256, 0, stream>>>(Ww, Wb, Uw, Ub, bv,
                                        U_hi, U_lo, W_hi, W_lo, bias, h_hi, h_lo, flags);

    rnn_xp_gemm<<<4096, 256, 0, stream>>>(X, W_hi, W_lo, bias, Out);

    void* args[] = { (void*)&U_hi, (void*)&U_lo, (void*)&h_hi, (void*)&h_lo,
                     (void*)&Out, (void*)&flags };
    hipLaunchCooperativeKernel((const void*)rnn_recur, dim3(NBLK), dim3(512), args, 0, stream);
}

// Round 4
// 5138.854 us; speedup vs baseline: 3.5097x; 1.0484x over previous
//
#include <hip/hip_runtime.h>

typedef __attribute__((ext_vector_type(8))) short bf16x8;
typedef __attribute__((ext_vector_type(4))) float f32x4;

#define MFMA16(a, b, c) __builtin_amdgcn_mfma_f32_16x16x32_bf16(a, b, c, 0, 0, 0)

#define HSZ (64 * 2048)     // one h buffer (elements)
#define NBLK 256            // recur grid: 4 mq-groups x 64 col-stripes

__device__ __forceinline__ unsigned short f2bf(float v) {
    unsigned int u = __float_as_uint(v);
    u += 0x7fffu + ((u >> 16) & 1u);   // round-to-nearest-even
    return (unsigned short)(u >> 16);
}
__device__ __forceinline__ float bf2f(unsigned short b) {
    return __uint_as_float(((unsigned int)b) << 16);
}

// coherent (L1/L2-bypassing, Infinity-Cache-point) accessors
__device__ __forceinline__ unsigned long long ald64(const void* p) {
    return __hip_atomic_load((const unsigned long long*)p, __ATOMIC_RELAXED,
                             __HIP_MEMORY_SCOPE_AGENT);
}
__device__ __forceinline__ unsigned int ald32(const void* p) {
    return __hip_atomic_load((const unsigned int*)p, __ATOMIC_RELAXED,
                             __HIP_MEMORY_SCOPE_AGENT);
}
__device__ __forceinline__ void ast32(void* p, unsigned int v) {
    __hip_atomic_store((unsigned int*)p, v, __ATOMIC_RELAXED,
                       __HIP_MEMORY_SCOPE_AGENT);
}

// ---------------- prep: split weights into bf16 hi/lo, fuse biases, zero h+flags ----------------
__global__ __launch_bounds__(256) void rnn_prep(
    const float* __restrict__ Ww, const float* __restrict__ Wb,
    const float* __restrict__ Uw, const float* __restrict__ Ub,
    const float* __restrict__ bv,
    unsigned short* __restrict__ U_hi, unsigned short* __restrict__ U_lo,
    unsigned short* __restrict__ W_hi, unsigned short* __restrict__ W_lo,
    float* __restrict__ bias,
    unsigned short* __restrict__ h_hi, unsigned short* __restrict__ h_lo,
    unsigned int* __restrict__ flags)
{
    size_t i = (size_t)blockIdx.x * 256 + threadIdx.x;
    if (i < (size_t)2048 * 2048) {
        float v = Uw[i];
        unsigned short hi = f2bf(v);
        U_hi[i] = hi;
        U_lo[i] = f2bf(v - bf2f(hi));
    }
    if (i < (size_t)2048 * 1024) {
        float v = Ww[i];
        unsigned short hi = f2bf(v);
        W_hi[i] = hi;
        W_lo[i] = f2bf(v - bf2f(hi));
    }
    if (i < 2 * HSZ) { h_hi[i] = 0; h_lo[i] = 0; }   // zero BOTH double buffers
    if (i < 2048) bias[i] = Wb[i] + Ub[i] + bv[i];
    if (i < NBLK * 16) ast32(&flags[i], 0);          // coherent zero of barrier flags
}

// ---------------- phase B: Xp = X @ Ww^T + bias  (M=32768, N=2048, K=1024) ----------------
#define PB_PAD 72  // LDS row stride in elems (144B): 2-way-max bank conflicts, 16B aligned

__global__ __launch_bounds__(256, 2) void rnn_xp_gemm(
    const float* __restrict__ X,
    const unsigned short* __restrict__ W_hi, const unsigned short* __restrict__ W_lo,
    const float* __restrict__ bias, float* __restrict__ Xp)
{
    __shared__ unsigned short a_hi[128 * PB_PAD], a_lo[128 * PB_PAD];
    __shared__ unsigned short b_hi[128 * PB_PAD], b_lo[128 * PB_PAD];

    const int wg = blockIdx.x;
    const int nblk = (wg & 15) << 7;   // 16 col blocks
    const int mblk = (wg >> 4) << 7;   // 256 row blocks
    const int tid = threadIdx.x;
    const int lane = tid & 63, w = tid >> 6;
    const int wm = (w & 1) << 6, wn = (w >> 1) << 6;
    const int lhi = lane >> 4, llo = lane & 15;

    f32x4 acc[4][4] = {};

    const int srow = tid >> 1;          // 0..127
    const int skh  = (tid & 1) << 5;    // 0 or 32 within BK=64

    for (int kb = 0; kb < 1024; kb += 64) {
        __syncthreads();
        {
            const float* src = X + (size_t)(mblk + srow) * 1024 + kb + skh;
            #pragma unroll
            for (int j = 0; j < 4; ++j) {
                bf16x8 vh, vl;
                #pragma unroll
                for (int e = 0; e < 8; ++e) {
                    float v = src[j * 8 + e];
                    unsigned short hi = f2bf(v);
                    vh[e] = (short)hi;
                    vl[e] = (short)f2bf(v - bf2f(hi));
                }
                *(bf16x8*)&a_hi[srow * PB_PAD + skh + j * 8] = vh;
                *(bf16x8*)&a_lo[srow * PB_PAD + skh + j * 8] = vl;
            }
        }
        {
            const unsigned short* sh = W_hi + (size_t)(nblk + srow) * 1024 + kb + skh;
            const unsigned short* sl = W_lo + (size_t)(nblk + srow) * 1024 + kb + skh;
            #pragma unroll
            for (int j = 0; j < 4; ++j) {
                *(bf16x8*)&b_hi[srow * PB_PAD + skh + j * 8] = *(const bf16x8*)&sh[j * 8];
                *(bf16x8*)&b_lo[srow * PB_PAD + skh + j * 8] = *(const bf16x8*)&sl[j * 8];
            }
        }
        __syncthreads();

        #pragma unroll
        for (int ks = 0; ks < 2; ++ks) {
            const int koff = ks * 32 + lhi * 8;
            bf16x8 afh[4], afl[4], bfh[4], bfl[4];
            #pragma unroll
            for (int m = 0; m < 4; ++m) {
                afh[m] = *(const bf16x8*)&a_hi[(wm + m * 16 + llo) * PB_PAD + koff];
                afl[m] = *(const bf16x8*)&a_lo[(wm + m * 16 + llo) * PB_PAD + koff];
            }
            #pragma unroll
            for (int n = 0; n < 4; ++n) {
                bfh[n] = *(const bf16x8*)&b_hi[(wn + n * 16 + llo) * PB_PAD + koff];
                bfl[n] = *(const bf16x8*)&b_lo[(wn + n * 16 + llo) * PB_PAD + koff];
            }
            #pragma unroll
            for (int m = 0; m < 4; ++m) {
                #pragma unroll
                for (int n = 0; n < 4; ++n) {
                    acc[m][n] = MFMA16(afh[m], bfh[n], acc[m][n]);
                    acc[m][n] = MFMA16(afh[m], bfl[n], acc[m][n]);
                    acc[m][n] = MFMA16(afl[m], bfh[n], acc[m][n]);
                }
            }
        }
    }

    #pragma unroll
    for (int n = 0; n < 4; ++n) {
        const int col = nblk + wn + n * 16 + llo;
        const float bvv = bias[col];
        #pragma unroll
        for (int m = 0; m < 4; ++m) {
            const int row0 = mblk + wm + m * 16 + lhi * 4;
            #pragma unroll
            for (int r = 0; r < 4; ++r)
                Xp[(size_t)(row0 + r) * 2048 + col] = acc[m][n][r] + bvv;
        }
    }
}

// ---------------- phase C: recurrent h_t = tanh(Xp[t] + h_{t-1} @ Uw^T) ----------------
// 256 wgs x 512 thr. Blocks (mq, sp) only exchange h-rows within their mq-group
// (64 blocks) -> 4 INDEPENDENT single-hop barriers: arrive-store + each block's
// wave 0 polls its group's 64 flags directly (no central gather/release).
// Cross-block h via relaxed AGENT-scope atomics (IF$-coherent, bypass L1/L2);
// __syncthreads() drains vmcnt so the arrive flag implies h-store visibility.
__global__ __launch_bounds__(512, 2) void rnn_recur(
    const unsigned short* __restrict__ U_hi, const unsigned short* __restrict__ U_lo,
    unsigned short* __restrict__ h_hi, unsigned short* __restrict__ h_lo,
    float* __restrict__ Out, unsigned int* __restrict__ flags)
{
    const int W = blockIdx.x;      // 0..255
    const int mq = W & 3;          // 16-row block of batch
    const int sp = W >> 2;         // 0..63: 32-col stripe
    const int tid = threadIdx.x;
    const int w = tid >> 6, lane = tid & 63;
    const int lhi = lane >> 4, llo = lane & 15;
    const int k0 = w << 8;         // 256 K per wave
    const int n0 = sp << 5;        // 32 cols

    // preload U fragments into registers (plain loads, L2-warm) and PIN them:
    bf16x8 ubh[8][2], ubl[8][2];
    #pragma unroll
    for (int ks = 0; ks < 8; ++ks) {
        #pragma unroll
        for (int n = 0; n < 2; ++n) {
            size_t off = (size_t)(n0 + n * 16 + llo) * 2048 + k0 + ks * 32 + lhi * 8;
            ubh[ks][n] = *(const bf16x8*)(U_hi + off);
            ubl[ks][n] = *(const bf16x8*)(U_lo + off);
            asm volatile("" : "+v"(ubh[ks][n]), "+v"(ubl[ks][n]));
        }
    }

    __shared__ float red[8][16][32];
    const int arow = (mq * 16 + llo) * 2048;

    const int colall = tid & 31;
    const int rrow = tid >> 5;             // 0..15
    const int b_out = mq * 16 + rrow;
    const int ng = n0 + colall;
    const size_t hidx = (size_t)b_out * 2048 + ng;

    unsigned int* myflag = &flags[(mq * 64 + sp) * 16];
    unsigned int* grpflags = &flags[(size_t)mq * 64 * 16];

    union Pack { unsigned long long q[2]; bf16x8 v; };

    for (int t = 0; t < 512; ++t) {
        const int cur = t & 1, nxt = cur ^ 1;
        const unsigned short* hh_r = h_hi + cur * HSZ;
        const unsigned short* hl_r = h_lo + cur * HSZ;
        unsigned short* hh_w = h_hi + nxt * HSZ;
        unsigned short* hl_w = h_lo + nxt * HSZ;

        const size_t oidx = ((size_t)t * 64 + b_out) * 2048 + ng;
        const float xp = Out[oidx];   // prefetch Xp early: independent of h

        f32x4 acc0 = {0, 0, 0, 0}, acc1 = {0, 0, 0, 0};
        #pragma unroll
        for (int ks = 0; ks < 8; ++ks) {
            const int k = k0 + ks * 32 + lhi * 8;
            Pack ph, pl;
            ph.q[0] = ald64(hh_r + arow + k);
            ph.q[1] = ald64(hh_r + arow + k + 4);
            pl.q[0] = ald64(hl_r + arow + k);
            pl.q[1] = ald64(hl_r + arow + k + 4);
            acc0 = MFMA16(ph.v, ubh[ks][0], acc0);
            acc0 = MFMA16(ph.v, ubl[ks][0], acc0);
            acc0 = MFMA16(pl.v, ubh[ks][0], acc0);
            acc1 = MFMA16(ph.v, ubh[ks][1], acc1);
            acc1 = MFMA16(ph.v, ubl[ks][1], acc1);
            acc1 = MFMA16(pl.v, ubh[ks][1], acc1);
        }
        #pragma unroll
        for (int r = 0; r < 4; ++r) {
            red[w][lhi * 4 + r][llo]      = acc0[r];
            red[w][lhi * 4 + r][16 + llo] = acc1[r];
        }
        __syncthreads();
        float s = 0.f;
        #pragma unroll
        for (int q = 0; q < 8; ++q) s += red[q][rrow][colall];
        const float hv = tanhf(s + xp);

        // h-store FIRST (it is what the barrier must order)
        const unsigned int hhp = f2bf(hv);
        const unsigned int hlp = f2bf(hv - bf2f((unsigned short)hhp));
        const unsigned int hh_o = (unsigned int)__shfl_xor((int)hhp, 1);
        const unsigned int hl_o = (unsigned int)__shfl_xor((int)hlp, 1);
        if (!(colall & 1)) {
            ast32((void*)(hh_w + hidx), hhp | (hh_o << 16));
            ast32((void*)(hl_w + hidx), hlp | (hl_o << 16));
        }

        __syncthreads();   // drains vmcnt: this block's h-stores visible at IF$
        if (tid == 0) ast32(myflag, (unsigned)(t + 1));
        Out[oidx] = hv;    // plain store; no ordering needed, drains next step

        // single-hop gather: wave 0 polls all 64 group flags (1 line/lane)
        if (tid < 64) {
            while (ald32(&grpflags[tid * 16]) < (unsigned)(t + 1)) {}
        }
        __syncthreads();
    }
}

// ---------------- launcher ----------------
extern "C" void kernel_launch(void* const* d_in, const int* in_sizes, int n_in,
                              void* d_out, int out_size, void* d_ws, size_t ws_size,
                              hipStream_t stream)
{
    const float* X  = (const float*)d_in[0];
    const float* Ww = (const float*)d_in[1];
    const float* Wb = (const float*)d_in[2];
    const float* Uw = (const float*)d_in[3];
    const float* Ub = (const float*)d_in[4];
    const float* bv = (const float*)d_in[5];
    float* Out = (float*)d_out;

    unsigned short* U_hi = (unsigned short*)d_ws;
    unsigned short* U_lo = U_hi + (size_t)2048 * 2048;
    unsigned short* W_hi = U_lo + (size_t)2048 * 2048;
    unsigned short* W_lo = W_hi + (size_t)2048 * 1024;
    float* bias = (float*)(W_lo + (size_t)2048 * 1024);
    unsigned short* h_hi = (unsigned short*)(bias + 2048);   // [2][HSZ]
    unsigned short* h_lo = h_hi + 2 * HSZ;                   // [2][HSZ]
    unsigned int* flags = (unsigned int*)(h_lo + 2 * HSZ);   // [256*16]

    rnn_prep<<<16384, 256, 0, stream>>>(Ww, Wb, Uw, Ub, bv,
                                        U_hi, U_lo, W_hi, W_lo, bias, h_hi, h_lo, flags);

    rnn_xp_gemm<<<4096, 256, 0, stream>>>(X, W_hi, W_lo, bias, Out);

    void* args[] = { (void*)&U_hi, (void*)&U_lo, (void*)&h_hi, (void*)&h_lo,
                     (void*)&Out, (void*)&flags };
    hipLaunchCooperativeKernel((const void*)rnn_recur, dim3(NBLK), dim3(512), args, 0, stream);
}